// Round 1
// baseline (1186.645 us; speedup 1.0000x reference)
//
#include <hip/hip_runtime.h>

#define LEAKY 0.2f
#define BN_EPS 1e-5f

// ---------- wave helpers (wave64) ----------
__device__ __forceinline__ float wsum(float v) {
#pragma unroll
  for (int o = 32; o > 0; o >>= 1) v += __shfl_xor(v, o, 64);
  return v;
}
__device__ __forceinline__ float wmax(float v) {
#pragma unroll
  for (int o = 32; o > 0; o >>= 1) v = fmaxf(v, __shfl_xor(v, o, 64));
  return v;
}

// edge_index may be int64 (reference dtype) or int32 (JAX x64 disabled).
__device__ __forceinline__ int edge_at(const void* ei, int is64, long long i) {
  return is64 ? (int)((const long long*)ei)[i] : ((const int*)ei)[i];
}

// ---------- probe: detect int32 vs int64 edge_index ----------
__global__ void k_probe(const void* ei, int N, int* flag) {
  if (threadIdx.x == 0 && blockIdx.x == 0) {
    const long long* p = (const long long*)ei;
    int ok = 1;
    for (int i = 0; i < 64; ++i) {
      long long v = p[i];
      if (v < 0 || v >= (long long)N) { ok = 0; break; }
    }
    *flag = ok;  // 1 => int64 layout, 0 => int32 layout
  }
}

// ---------- CSR build ----------
__global__ void k_deginit(int* deg, int N) {
  int i = blockIdx.x * blockDim.x + threadIdx.x;
  if (i < N) deg[i] = 1;  // self-loop
}

__global__ void k_hist(const void* ei, const int* flag, int E, int* deg) {
  int i = blockIdx.x * blockDim.x + threadIdx.x;
  if (i >= E) return;
  int is64 = *flag;
  int d = edge_at(ei, is64, (long long)E + i);
  atomicAdd(&deg[d], 1);
}

__global__ __launch_bounds__(1024) void k_scan(const int* deg, int N, int* rowptr, int* cursor) {
  __shared__ int bsum[1024];
  int tid = threadIdx.x;
  int chunk = (N + 1023) / 1024;
  int lo = tid * chunk;
  int hi = lo + chunk; if (hi > N) hi = N;
  int s = 0;
  for (int i = lo; i < hi && i >= 0; ++i) s += deg[i];
  bsum[tid] = s;
  __syncthreads();
  for (int off = 1; off < 1024; off <<= 1) {
    int add = (tid >= off) ? bsum[tid - off] : 0;
    __syncthreads();
    bsum[tid] += add;
    __syncthreads();
  }
  int run = (tid == 0) ? 0 : bsum[tid - 1];
  for (int i = lo; i < hi && i >= 0; ++i) {
    rowptr[i] = run; cursor[i] = run; run += deg[i];
  }
  if (tid == 1023) rowptr[N] = bsum[1023];
}

__global__ void k_scatter(const void* ei, const int* flag, int E, int N, int* cursor, int* col) {
  int i = blockIdx.x * blockDim.x + threadIdx.x;
  if (i >= E + N) return;
  int is64 = *flag;
  int s, d;
  if (i < E) {
    s = edge_at(ei, is64, (long long)i);
    d = edge_at(ei, is64, (long long)E + i);
  } else {
    s = d = i - E;  // self-loop
  }
  int pos = atomicAdd(&cursor[d], 1);
  col[pos] = s;
}

// ---------- BatchNorm stats ----------
__global__ __launch_bounds__(128) void k_bnstats(const float* __restrict__ x, int N, float* sums) {
  int f = threadIdx.x;  // 128 features
  float s = 0.f, s2 = 0.f;
  for (int r = blockIdx.x; r < N; r += gridDim.x) {
    float v = x[(size_t)r * 128 + f];
    s += v; s2 += v * v;
  }
  atomicAdd(&sums[f], s);
  atomicAdd(&sums[128 + f], s2);
}

__global__ void k_bnfin(const float* sums, const float* __restrict__ gamma,
                        const float* __restrict__ beta, int N, float* scale, float* shift) {
  int f = threadIdx.x;  // 128
  float inv_n = 1.0f / (float)N;
  float mu = sums[f] * inv_n;
  float var = sums[128 + f] * inv_n - mu * mu;
  float rs = rsqrtf(var + BN_EPS);
  float sc = gamma[f] * rs;
  scale[f] = sc;
  shift[f] = beta[f] - mu * sc;
}

// ---------- fused BN-apply + dual matmul: [h | lin] = xn @ [W | LW] ----------
// block: 256 threads; tile 32 rows x 256 cols; per-thread 8 rows x 4 cols.
#define MM_ROWS 32
__global__ __launch_bounds__(256) void k_matmul(
    const float* __restrict__ x, const float* __restrict__ scale, const float* __restrict__ shift,
    const float* __restrict__ W, const float* __restrict__ LW,
    float* __restrict__ h, float* __restrict__ lin, int N) {
  __shared__ __align__(16) float xrow[MM_ROWS][132];  // +4 pad, row stride 528B (16B aligned)
  __shared__ __align__(16) float wbuf[32][256];       // k-chunk of [W|LW]
  int tid = threadIdx.x;
  int tx = tid & 63;   // col quad: cols 4*tx..4*tx+3
  int ty = tid >> 6;   // 0..3: rows ty*8..ty*8+7
  int rowBase = blockIdx.x * MM_ROWS;

  // stage x tile with BN affine applied (coalesced float4)
  for (int q = tid; q < MM_ROWS * 32; q += 256) {
    int r = q >> 5, kq = q & 31;
    int row = rowBase + r;
    float4 v = make_float4(0.f, 0.f, 0.f, 0.f);
    if (row < N) v = *(const float4*)&x[(size_t)row * 128 + kq * 4];
    float4 sc = *(const float4*)&scale[kq * 4];
    float4 sh = *(const float4*)&shift[kq * 4];
    float4 o;
    o.x = v.x * sc.x + sh.x; o.y = v.y * sc.y + sh.y;
    o.z = v.z * sc.z + sh.z; o.w = v.w * sc.w + sh.w;
    *(float4*)&xrow[r][kq * 4] = o;
  }

  float acc[8][4];
#pragma unroll
  for (int r = 0; r < 8; ++r)
#pragma unroll
    for (int c = 0; c < 4; ++c) acc[r][c] = 0.f;

  for (int kc = 0; kc < 4; ++kc) {
    __syncthreads();
    // stage w chunk: k in [kc*32, kc*32+32), all 256 cols
    for (int q = tid; q < 32 * 64; q += 256) {
      int kk = q >> 6, cq = q & 63;
      int k = kc * 32 + kk, c = cq * 4;
      float4 wv;
      if (c < 128) wv = *(const float4*)&W[(size_t)k * 128 + c];
      else         wv = *(const float4*)&LW[(size_t)k * 128 + (c - 128)];
      *(float4*)&wbuf[kk][c] = wv;
    }
    __syncthreads();
#pragma unroll
    for (int k4 = 0; k4 < 8; ++k4) {
      float4 w0 = *(const float4*)&wbuf[k4 * 4 + 0][tx * 4];
      float4 w1 = *(const float4*)&wbuf[k4 * 4 + 1][tx * 4];
      float4 w2 = *(const float4*)&wbuf[k4 * 4 + 2][tx * 4];
      float4 w3 = *(const float4*)&wbuf[k4 * 4 + 3][tx * 4];
#pragma unroll
      for (int r = 0; r < 8; ++r) {
        float4 xv = *(const float4*)&xrow[ty * 8 + r][kc * 32 + k4 * 4];
        acc[r][0] += xv.x * w0.x + xv.y * w1.x + xv.z * w2.x + xv.w * w3.x;
        acc[r][1] += xv.x * w0.y + xv.y * w1.y + xv.z * w2.y + xv.w * w3.y;
        acc[r][2] += xv.x * w0.z + xv.y * w1.z + xv.z * w2.z + xv.w * w3.z;
        acc[r][3] += xv.x * w0.w + xv.y * w1.w + xv.z * w2.w + xv.w * w3.w;
      }
    }
  }
#pragma unroll
  for (int r = 0; r < 8; ++r) {
    int row = rowBase + ty * 8 + r;
    if (row >= N) continue;
    float4 v = make_float4(acc[r][0], acc[r][1], acc[r][2], acc[r][3]);
    int c = tx * 4;
    if (c < 128) *(float4*)&h[(size_t)row * 128 + c] = v;
    else         *(float4*)&lin[(size_t)row * 128 + (c - 128)] = v;
  }
}

// ---------- es/ed per node (2 heads, 64 feats each) ----------
__global__ __launch_bounds__(256) void k_esed(const float* __restrict__ h,
                                              const float* __restrict__ as_, const float* __restrict__ ad_,
                                              float* es, float* ed, int N) {
  int lane = threadIdx.x & 63;
  int n = blockIdx.x * 4 + (threadIdx.x >> 6);
  if (n >= N) return;
  float h0 = h[(size_t)n * 128 + lane];
  float h1 = h[(size_t)n * 128 + 64 + lane];
  float e0 = wsum(h0 * as_[lane]);
  float e1 = wsum(h1 * as_[64 + lane]);
  float d0 = wsum(h0 * ad_[lane]);
  float d1 = wsum(h1 * ad_[64 + lane]);
  if (lane == 0) {
    es[2 * n] = e0; es[2 * n + 1] = e1;
    ed[2 * n] = d0; ed[2 * n + 1] = d1;
  }
}

// ---------- edge aggregation + combine (layers 1&2); one wave per dst ----------
__global__ __launch_bounds__(256) void k_agg(
    const int* __restrict__ rowptr, const int* __restrict__ col,
    const float* __restrict__ es, const float* __restrict__ ed,
    const float* __restrict__ h, const float* __restrict__ lin,
    const float* __restrict__ lb, const float* __restrict__ gb,
    float* __restrict__ xout, int N) {
  int lane = threadIdx.x & 63;
  int d = blockIdx.x * 4 + (threadIdx.x >> 6);
  if (d >= N) return;
  int start = rowptr[d], end = rowptr[d + 1];
  float ed0 = ed[2 * d], ed1 = ed[2 * d + 1];

  // pass 1: segment max (edge-parallel)
  float m0 = -1e30f, m1 = -1e30f;
  for (int i = start + lane; i < end; i += 64) {
    int s = col[i];
    float e0 = es[2 * s] + ed0;     e0 = e0 > 0.f ? e0 : LEAKY * e0;
    float e1 = es[2 * s + 1] + ed1; e1 = e1 > 0.f ? e1 : LEAKY * e1;
    m0 = fmaxf(m0, e0); m1 = fmaxf(m1, e1);
  }
  m0 = wmax(m0); m1 = wmax(m1);

  // pass 2: sum of exp (edge-parallel)
  float s0 = 0.f, s1 = 0.f;
  for (int i = start + lane; i < end; i += 64) {
    int s = col[i];
    float e0 = es[2 * s] + ed0;     e0 = e0 > 0.f ? e0 : LEAKY * e0;
    float e1 = es[2 * s + 1] + ed1; e1 = e1 > 0.f ? e1 : LEAKY * e1;
    s0 += __expf(e0 - m0); s1 += __expf(e1 - m1);
  }
  s0 = wsum(s0); s1 = wsum(s1);
  float inv0 = 1.0f / s0, inv1 = 1.0f / s1;

  // pass 3: weighted gather (feature-parallel; edges sequential)
  float acc0 = 0.f, acc1 = 0.f;
  for (int i = start; i < end; ++i) {
    int s = col[i];  // wave-uniform load
    float e0 = es[2 * s] + ed0;     e0 = e0 > 0.f ? e0 : LEAKY * e0;
    float e1 = es[2 * s + 1] + ed1; e1 = e1 > 0.f ? e1 : LEAKY * e1;
    float w0 = __expf(e0 - m0) * inv0;
    float w1 = __expf(e1 - m1) * inv1;
    acc0 += w0 * h[(size_t)s * 128 + lane];
    acc1 += w1 * h[(size_t)s * 128 + 64 + lane];
  }
  size_t b = (size_t)d * 128;
  float v0 = lin[b + lane] + lb[lane] + acc0 + gb[lane];
  float v1 = lin[b + 64 + lane] + lb[64 + lane] + acc1 + gb[64 + lane];
  xout[b + lane] = v0 > 0.f ? v0 : 0.f;
  xout[b + 64 + lane] = v1 > 0.f ? v1 : 0.f;
}

// ---------- layer 3: BN-apply + tiny matmul + es/ed (1 head, 2 out feats) ----------
__global__ __launch_bounds__(256) void k_l3node(
    const float* __restrict__ x, const float* __restrict__ scale, const float* __restrict__ shift,
    const float* __restrict__ W3, const float* __restrict__ LW3,
    const float* __restrict__ as3, const float* __restrict__ ad3,
    float* h3, float* lin3, float* es3, float* ed3, int N) {
  int lane = threadIdx.x & 63;
  int n = blockIdx.x * 4 + (threadIdx.x >> 6);
  if (n >= N) return;
  float xn0 = x[(size_t)n * 128 + lane] * scale[lane] + shift[lane];
  float xn1 = x[(size_t)n * 128 + 64 + lane] * scale[64 + lane] + shift[64 + lane];
  float2 w0 = *(const float2*)&W3[lane * 2];
  float2 w1 = *(const float2*)&W3[(64 + lane) * 2];
  float2 l0 = *(const float2*)&LW3[lane * 2];
  float2 l1 = *(const float2*)&LW3[(64 + lane) * 2];
  float hc0 = wsum(xn0 * w0.x + xn1 * w1.x);
  float hc1 = wsum(xn0 * w0.y + xn1 * w1.y);
  float lc0 = wsum(xn0 * l0.x + xn1 * l1.x);
  float lc1 = wsum(xn0 * l0.y + xn1 * l1.y);
  if (lane == 0) {
    h3[2 * n] = hc0; h3[2 * n + 1] = hc1;
    lin3[2 * n] = lc0; lin3[2 * n + 1] = lc1;
    es3[n] = hc0 * as3[0] + hc1 * as3[1];
    ed3[n] = hc0 * ad3[0] + hc1 * ad3[1];
  }
}

// ---------- layer 3 edge aggregation + final output ----------
__global__ __launch_bounds__(256) void k_agg3(
    const int* __restrict__ rowptr, const int* __restrict__ col,
    const float* __restrict__ es, const float* __restrict__ ed,
    const float* __restrict__ h3, const float* __restrict__ lin3,
    const float* __restrict__ lb3, const float* __restrict__ gb3,
    float* __restrict__ out, int N) {
  int lane = threadIdx.x & 63;
  int d = blockIdx.x * 4 + (threadIdx.x >> 6);
  if (d >= N) return;
  int start = rowptr[d], end = rowptr[d + 1];
  float edd = ed[d];
  float m = -1e30f;
  for (int i = start + lane; i < end; i += 64) {
    int s = col[i];
    float e = es[s] + edd; e = e > 0.f ? e : LEAKY * e;
    m = fmaxf(m, e);
  }
  m = wmax(m);
  float ps = 0.f, a0 = 0.f, a1 = 0.f;
  for (int i = start + lane; i < end; i += 64) {
    int s = col[i];
    float e = es[s] + edd; e = e > 0.f ? e : LEAKY * e;
    float p = __expf(e - m);
    ps += p; a0 += p * h3[2 * s]; a1 += p * h3[2 * s + 1];
  }
  ps = wsum(ps); a0 = wsum(a0); a1 = wsum(a1);
  if (lane < 2) {
    float a = (lane == 0 ? a0 : a1) / ps;
    float v = lin3[2 * d + lane] + lb3[lane] + a + gb3[lane];
    out[2 * d + lane] = v > 0.f ? v : 0.f;
  }
}

extern "C" void kernel_launch(void* const* d_in, const int* in_sizes, int n_in,
                              void* d_out, int out_size, void* d_ws, size_t ws_size,
                              hipStream_t stream) {
  const float* x   = (const float*)d_in[0];
  const void*  ei  = d_in[1];
  const float* W1  = (const float*)d_in[2];
  const float* as1 = (const float*)d_in[3];
  const float* ad1 = (const float*)d_in[4];
  const float* gb1 = (const float*)d_in[5];
  const float* lw1 = (const float*)d_in[6];
  const float* lb1 = (const float*)d_in[7];
  const float* bg1 = (const float*)d_in[8];
  const float* bb1 = (const float*)d_in[9];
  const float* W2  = (const float*)d_in[10];
  const float* as2 = (const float*)d_in[11];
  const float* ad2 = (const float*)d_in[12];
  const float* gb2 = (const float*)d_in[13];
  const float* lw2 = (const float*)d_in[14];
  const float* lb2 = (const float*)d_in[15];
  const float* bg2 = (const float*)d_in[16];
  const float* bb2 = (const float*)d_in[17];
  const float* W3  = (const float*)d_in[18];
  const float* as3 = (const float*)d_in[19];
  const float* ad3 = (const float*)d_in[20];
  const float* gb3 = (const float*)d_in[21];
  const float* lw3 = (const float*)d_in[22];
  const float* lb3 = (const float*)d_in[23];
  const float* bg3 = (const float*)d_in[24];
  const float* bb3 = (const float*)d_in[25];
  float* out = (float*)d_out;

  int N = in_sizes[0] / 128;
  int E = in_sizes[1] / 2;

  // workspace carve-out (256B aligned slabs)
  char* w = (char*)d_ws;
  size_t off = 0;
  auto alloc = [&](size_t bytes) -> void* {
    void* p = w + off;
    off = (off + bytes + 255) & ~(size_t)255;
    return p;
  };
  int* flag    = (int*)alloc(4);
  int* deg     = (int*)alloc((size_t)N * 4);
  int* rowptr  = (int*)alloc(((size_t)N + 1) * 4);
  int* cursor  = (int*)alloc((size_t)N * 4);
  int* col     = (int*)alloc((size_t)(E + N) * 4);
  float* sums  = (float*)alloc(3 * 256 * 4);   // per layer: [sum(128) | sumsq(128)]
  float* scl   = (float*)alloc(3 * 256 * 4);   // per layer: [scale(128) | shift(128)]
  float* h     = (float*)alloc((size_t)N * 128 * 4);
  float* lin   = (float*)alloc((size_t)N * 128 * 4);
  float* x2    = (float*)alloc((size_t)N * 128 * 4);  // layer1 output, then reused for layer2 output
  float* es    = (float*)alloc((size_t)N * 2 * 4);
  float* edb   = (float*)alloc((size_t)N * 2 * 4);
  float* h3    = (float*)alloc((size_t)N * 2 * 4);
  float* lin3  = (float*)alloc((size_t)N * 2 * 4);
  float* es3   = (float*)alloc((size_t)N * 4);
  float* ed3   = (float*)alloc((size_t)N * 4);
  (void)ws_size; (void)n_in; (void)out_size;

  hipMemsetAsync(sums, 0, 3 * 256 * 4, stream);

  // CSR build (shared across all 3 layers)
  k_probe<<<1, 64, 0, stream>>>(ei, N, flag);
  k_deginit<<<(N + 255) / 256, 256, 0, stream>>>(deg, N);
  k_hist<<<(E + 255) / 256, 256, 0, stream>>>(ei, flag, E, deg);
  k_scan<<<1, 1024, 0, stream>>>(deg, N, rowptr, cursor);
  k_scatter<<<(E + N + 255) / 256, 256, 0, stream>>>(ei, flag, E, N, cursor, col);

  int gnode = (N + 3) / 4;
  int gmm = (N + MM_ROWS - 1) / MM_ROWS;

  // ---- layer 1 ----
  k_bnstats<<<256, 128, 0, stream>>>(x, N, sums);
  k_bnfin<<<1, 128, 0, stream>>>(sums, bg1, bb1, N, scl, scl + 128);
  k_matmul<<<gmm, 256, 0, stream>>>(x, scl, scl + 128, W1, lw1, h, lin, N);
  k_esed<<<gnode, 256, 0, stream>>>(h, as1, ad1, es, edb, N);
  k_agg<<<gnode, 256, 0, stream>>>(rowptr, col, es, edb, h, lin, lb1, gb1, x2, N);

  // ---- layer 2 ----
  k_bnstats<<<256, 128, 0, stream>>>(x2, N, sums + 256);
  k_bnfin<<<1, 128, 0, stream>>>(sums + 256, bg2, bb2, N, scl + 256, scl + 384);
  k_matmul<<<gmm, 256, 0, stream>>>(x2, scl + 256, scl + 384, W2, lw2, h, lin, N);
  k_esed<<<gnode, 256, 0, stream>>>(h, as2, ad2, es, edb, N);
  k_agg<<<gnode, 256, 0, stream>>>(rowptr, col, es, edb, h, lin, lb2, gb2, x2, N);

  // ---- layer 3 ----
  k_bnstats<<<256, 128, 0, stream>>>(x2, N, sums + 512);
  k_bnfin<<<1, 128, 0, stream>>>(sums + 512, bg3, bb3, N, scl + 512, scl + 640);
  k_l3node<<<gnode, 256, 0, stream>>>(x2, scl + 512, scl + 640, W3, lw3, as3, ad3,
                                      h3, lin3, es3, ed3, N);
  k_agg3<<<gnode, 256, 0, stream>>>(rowptr, col, es3, ed3, h3, lin3, lb3, gb3, out, N);
}

// Round 2
// 888.802 us; speedup vs baseline: 1.3351x; 1.3351x over previous
//
#include <hip/hip_runtime.h>

#define LEAKY 0.2f
#define BN_EPS 1e-5f

// ---------- wave helpers (wave64) ----------
__device__ __forceinline__ float wsum(float v) {
#pragma unroll
  for (int o = 32; o > 0; o >>= 1) v += __shfl_xor(v, o, 64);
  return v;
}

// packed-bf16 decode: dword holds feat2j (low16) and feat2j+1 (high16)
__device__ __forceinline__ float blo(unsigned u) { return __uint_as_float(u << 16); }
__device__ __forceinline__ float bhi(unsigned u) { return __uint_as_float(u & 0xffff0000u); }
__device__ __forceinline__ unsigned pack_bf16(float a, float b) {
  unsigned ua = __float_as_uint(a), ub = __float_as_uint(b);
  ua = (ua + 0x7fffu + ((ua >> 16) & 1u)) >> 16;
  ub = (ub + 0x7fffu + ((ub >> 16) & 1u)) >> 16;
  return ua | (ub << 16);
}

// edge_index may be int64 (reference dtype) or int32 (JAX x64 disabled).
__device__ __forceinline__ int edge_at(const void* ei, int is64, long long i) {
  return is64 ? (int)((const long long*)ei)[i] : ((const int*)ei)[i];
}

// ---------- probe: detect int32 vs int64 edge_index ----------
__global__ void k_probe(const void* ei, int N, int* flag) {
  if (threadIdx.x == 0 && blockIdx.x == 0) {
    const long long* p = (const long long*)ei;
    int ok = 1;
    for (int i = 0; i < 64; ++i) {
      long long v = p[i];
      if (v < 0 || v >= (long long)N) { ok = 0; break; }
    }
    *flag = ok;  // 1 => int64 layout, 0 => int32 layout
  }
}

// ---------- CSR build ----------
__global__ void k_deginit(int* deg, int N) {
  int i = blockIdx.x * blockDim.x + threadIdx.x;
  if (i < N) deg[i] = 1;  // self-loop
}

__global__ void k_hist(const void* ei, const int* flag, int E, int* deg) {
  int i = blockIdx.x * blockDim.x + threadIdx.x;
  if (i >= E) return;
  int is64 = *flag;
  int d = edge_at(ei, is64, (long long)E + i);
  atomicAdd(&deg[d], 1);
}

__global__ __launch_bounds__(1024) void k_scan(const int* deg, int N, int* rowptr, int* cursor) {
  __shared__ int bsum[1024];
  int tid = threadIdx.x;
  int chunk = (N + 1023) / 1024;
  int lo = tid * chunk;
  int hi = lo + chunk; if (hi > N) hi = N;
  int s = 0;
  for (int i = lo; i < hi && i >= 0; ++i) s += deg[i];
  bsum[tid] = s;
  __syncthreads();
  for (int off = 1; off < 1024; off <<= 1) {
    int add = (tid >= off) ? bsum[tid - off] : 0;
    __syncthreads();
    bsum[tid] += add;
    __syncthreads();
  }
  int run = (tid == 0) ? 0 : bsum[tid - 1];
  for (int i = lo; i < hi && i >= 0; ++i) {
    rowptr[i] = run; cursor[i] = run; run += deg[i];
  }
  if (tid == 1023) rowptr[N] = bsum[1023];
}

__global__ void k_scatter(const void* ei, const int* flag, int E, int N, int* cursor, int* col) {
  int i = blockIdx.x * blockDim.x + threadIdx.x;
  if (i >= E + N) return;
  int is64 = *flag;
  int s, d;
  if (i < E) {
    s = edge_at(ei, is64, (long long)i);
    d = edge_at(ei, is64, (long long)E + i);
  } else {
    s = d = i - E;  // self-loop
  }
  int pos = atomicAdd(&cursor[d], 1);
  col[pos] = s;
}

// ---------- BatchNorm stats ----------
__global__ __launch_bounds__(128) void k_bnstats(const float* __restrict__ x, int N, float* sums) {
  int f = threadIdx.x;  // 128 features
  float s = 0.f, s2 = 0.f;
  for (int r = blockIdx.x; r < N; r += gridDim.x) {
    float v = x[(size_t)r * 128 + f];
    s += v; s2 += v * v;
  }
  atomicAdd(&sums[f], s);
  atomicAdd(&sums[128 + f], s2);
}

__global__ void k_bnfin(const float* sums, const float* __restrict__ gamma,
                        const float* __restrict__ beta, int N, float* scale, float* shift) {
  int f = threadIdx.x;  // 128
  float inv_n = 1.0f / (float)N;
  float mu = sums[f] * inv_n;
  float var = sums[128 + f] * inv_n - mu * mu;
  float rs = rsqrtf(var + BN_EPS);
  float sc = gamma[f] * rs;
  scale[f] = sc;
  shift[f] = beta[f] - mu * sc;
}

// ---------- fused BN-apply + dual matmul: [h | lin] = xn @ [W | LW] ----------
// block: 256 threads; tile 32 rows x 256 cols; per-thread 8 rows x 4 cols.
// Epilogue also emits packed-bf16 copy of h for the gather kernel.
#define MM_ROWS 32
__global__ __launch_bounds__(256) void k_matmul(
    const float* __restrict__ x, const float* __restrict__ scale, const float* __restrict__ shift,
    const float* __restrict__ W, const float* __restrict__ LW,
    float* __restrict__ h, unsigned* __restrict__ hb, float* __restrict__ lin, int N) {
  __shared__ __align__(16) float xrow[MM_ROWS][132];  // +4 pad
  __shared__ __align__(16) float wbuf[32][256];       // k-chunk of [W|LW]
  int tid = threadIdx.x;
  int tx = tid & 63;   // col quad: cols 4*tx..4*tx+3
  int ty = tid >> 6;   // 0..3: rows ty*8..ty*8+7
  int rowBase = blockIdx.x * MM_ROWS;

  for (int q = tid; q < MM_ROWS * 32; q += 256) {
    int r = q >> 5, kq = q & 31;
    int row = rowBase + r;
    float4 v = make_float4(0.f, 0.f, 0.f, 0.f);
    if (row < N) v = *(const float4*)&x[(size_t)row * 128 + kq * 4];
    float4 sc = *(const float4*)&scale[kq * 4];
    float4 sh = *(const float4*)&shift[kq * 4];
    float4 o;
    o.x = v.x * sc.x + sh.x; o.y = v.y * sc.y + sh.y;
    o.z = v.z * sc.z + sh.z; o.w = v.w * sc.w + sh.w;
    *(float4*)&xrow[r][kq * 4] = o;
  }

  float acc[8][4];
#pragma unroll
  for (int r = 0; r < 8; ++r)
#pragma unroll
    for (int c = 0; c < 4; ++c) acc[r][c] = 0.f;

  for (int kc = 0; kc < 4; ++kc) {
    __syncthreads();
    for (int q = tid; q < 32 * 64; q += 256) {
      int kk = q >> 6, cq = q & 63;
      int k = kc * 32 + kk, c = cq * 4;
      float4 wv;
      if (c < 128) wv = *(const float4*)&W[(size_t)k * 128 + c];
      else         wv = *(const float4*)&LW[(size_t)k * 128 + (c - 128)];
      *(float4*)&wbuf[kk][c] = wv;
    }
    __syncthreads();
#pragma unroll
    for (int k4 = 0; k4 < 8; ++k4) {
      float4 w0 = *(const float4*)&wbuf[k4 * 4 + 0][tx * 4];
      float4 w1 = *(const float4*)&wbuf[k4 * 4 + 1][tx * 4];
      float4 w2 = *(const float4*)&wbuf[k4 * 4 + 2][tx * 4];
      float4 w3 = *(const float4*)&wbuf[k4 * 4 + 3][tx * 4];
#pragma unroll
      for (int r = 0; r < 8; ++r) {
        float4 xv = *(const float4*)&xrow[ty * 8 + r][kc * 32 + k4 * 4];
        acc[r][0] += xv.x * w0.x + xv.y * w1.x + xv.z * w2.x + xv.w * w3.x;
        acc[r][1] += xv.x * w0.y + xv.y * w1.y + xv.z * w2.y + xv.w * w3.y;
        acc[r][2] += xv.x * w0.z + xv.y * w1.z + xv.z * w2.z + xv.w * w3.z;
        acc[r][3] += xv.x * w0.w + xv.y * w1.w + xv.z * w2.w + xv.w * w3.w;
      }
    }
  }
#pragma unroll
  for (int r = 0; r < 8; ++r) {
    int row = rowBase + ty * 8 + r;
    if (row >= N) continue;
    float4 v = make_float4(acc[r][0], acc[r][1], acc[r][2], acc[r][3]);
    int c = tx * 4;
    if (c < 128) {
      *(float4*)&h[(size_t)row * 128 + c] = v;
      uint2 pk;
      pk.x = pack_bf16(v.x, v.y);
      pk.y = pack_bf16(v.z, v.w);
      *(uint2*)&hb[(size_t)row * 64 + (c >> 1)] = pk;
    } else {
      *(float4*)&lin[(size_t)row * 128 + (c - 128)] = v;
    }
  }
}

// ---------- es/ed per node (2 heads, 64 feats each) ----------
__global__ __launch_bounds__(256) void k_esed(const float* __restrict__ h,
                                              const float* __restrict__ as_, const float* __restrict__ ad_,
                                              float* es, float* ed, int N) {
  int lane = threadIdx.x & 63;
  int n = blockIdx.x * 4 + (threadIdx.x >> 6);
  if (n >= N) return;
  float h0 = h[(size_t)n * 128 + lane];
  float h1 = h[(size_t)n * 128 + 64 + lane];
  float e0 = wsum(h0 * as_[lane]);
  float e1 = wsum(h1 * as_[64 + lane]);
  float d0 = wsum(h0 * ad_[lane]);
  float d1 = wsum(h1 * ad_[64 + lane]);
  if (lane == 0) {
    es[2 * n] = e0; es[2 * n + 1] = e1;
    ed[2 * n] = d0; ed[2 * n + 1] = d1;
  }
}

// ---------- edge aggregation + combine (layers 1&2); one wave per dst ----------
// No segment-max (values bounded; softmax ratio unchanged). Pass A computes
// exp-weights edge-parallel into LDS; pass B gathers packed-bf16 h rows with
// one coalesced 256B load per edge, 4-deep unroll; normalize in epilogue.
__global__ __launch_bounds__(256) void k_agg(
    const int* __restrict__ rowptr, const int* __restrict__ col,
    const float* __restrict__ es, const float* __restrict__ ed,
    const unsigned* __restrict__ hb, const float* __restrict__ lin,
    const float* __restrict__ lb, const float* __restrict__ gb,
    float* __restrict__ xout, int N) {
  __shared__ float2 pbuf[4][128];
  int lane = threadIdx.x & 63;
  int w = threadIdx.x >> 6;
  int d = blockIdx.x * 4 + w;
  if (d >= N) return;
  int start = rowptr[d], end = rowptr[d + 1];
  float2 edv = *(const float2*)&ed[2 * d];
  int head_hi = lane >= 32;

  // pass A: exp weights (edge-parallel), cache first 128 in LDS, sum
  float s0 = 0.f, s1 = 0.f;
  for (int i = start + lane; i < end; i += 64) {
    int s = col[i];
    float2 ev = *(const float2*)&es[2 * s];
    float e0 = ev.x + edv.x; e0 = e0 > 0.f ? e0 : LEAKY * e0;
    float e1 = ev.y + edv.y; e1 = e1 > 0.f ? e1 : LEAKY * e1;
    float p0 = __expf(e0), p1 = __expf(e1);
    int j = i - start;
    if (j < 128) pbuf[w][j] = make_float2(p0, p1);
    s0 += p0; s1 += p1;
  }
  s0 = wsum(s0); s1 = wsum(s1);
  float inv = 1.0f / (head_hi ? s1 : s0);

  // pass B: weighted gather, feature-parallel (lane -> feats 2*lane, 2*lane+1)
  float acc0 = 0.f, acc1 = 0.f;
  int bounded = end < start + 128 ? end : start + 128;
  int i = start;
  for (; i + 4 <= bounded; i += 4) {
    int j = i - start;
    int c0 = col[i], c1 = col[i + 1], c2 = col[i + 2], c3 = col[i + 3];
    float2 w0 = pbuf[w][j], w1 = pbuf[w][j + 1], w2 = pbuf[w][j + 2], w3 = pbuf[w][j + 3];
    unsigned u0 = hb[(size_t)c0 * 64 + lane];
    unsigned u1 = hb[(size_t)c1 * 64 + lane];
    unsigned u2 = hb[(size_t)c2 * 64 + lane];
    unsigned u3 = hb[(size_t)c3 * 64 + lane];
    float f0 = head_hi ? w0.y : w0.x;
    float f1 = head_hi ? w1.y : w1.x;
    float f2 = head_hi ? w2.y : w2.x;
    float f3 = head_hi ? w3.y : w3.x;
    acc0 = fmaf(f0, blo(u0), acc0); acc1 = fmaf(f0, bhi(u0), acc1);
    acc0 = fmaf(f1, blo(u1), acc0); acc1 = fmaf(f1, bhi(u1), acc1);
    acc0 = fmaf(f2, blo(u2), acc0); acc1 = fmaf(f2, bhi(u2), acc1);
    acc0 = fmaf(f3, blo(u3), acc0); acc1 = fmaf(f3, bhi(u3), acc1);
  }
  for (; i < bounded; ++i) {
    int j = i - start;
    int c0 = col[i];
    float2 w0 = pbuf[w][j];
    unsigned u0 = hb[(size_t)c0 * 64 + lane];
    float f0 = head_hi ? w0.y : w0.x;
    acc0 = fmaf(f0, blo(u0), acc0); acc1 = fmaf(f0, bhi(u0), acc1);
  }
  for (; i < end; ++i) {  // deg > 128 slow path (recompute weight)
    int s = col[i];
    float2 ev = *(const float2*)&es[2 * s];
    float e0 = ev.x + edv.x; e0 = e0 > 0.f ? e0 : LEAKY * e0;
    float e1 = ev.y + edv.y; e1 = e1 > 0.f ? e1 : LEAKY * e1;
    float p0 = __expf(e0), p1 = __expf(e1);
    float f0 = head_hi ? p1 : p0;
    unsigned u0 = hb[(size_t)s * 64 + lane];
    acc0 = fmaf(f0, blo(u0), acc0); acc1 = fmaf(f0, bhi(u0), acc1);
  }

  // epilogue: feats f=2*lane, f+1
  int f = 2 * lane;
  size_t b = (size_t)d * 128 + f;
  float2 lv = *(const float2*)&lin[b];
  float2 lbv = *(const float2*)&lb[f];
  float2 gbv = *(const float2*)&gb[f];
  float v0 = lv.x + lbv.x + acc0 * inv + gbv.x;
  float v1 = lv.y + lbv.y + acc1 * inv + gbv.y;
  float2 o; o.x = v0 > 0.f ? v0 : 0.f; o.y = v1 > 0.f ? v1 : 0.f;
  *(float2*)&xout[b] = o;
}

// ---------- layer 3: BN-apply + tiny matmul + es/ed (1 head, 2 out feats) ----------
__global__ __launch_bounds__(256) void k_l3node(
    const float* __restrict__ x, const float* __restrict__ scale, const float* __restrict__ shift,
    const float* __restrict__ W3, const float* __restrict__ LW3,
    const float* __restrict__ as3, const float* __restrict__ ad3,
    float* h3, float* lin3, float* es3, float* ed3, int N) {
  int lane = threadIdx.x & 63;
  int n = blockIdx.x * 4 + (threadIdx.x >> 6);
  if (n >= N) return;
  float xn0 = x[(size_t)n * 128 + lane] * scale[lane] + shift[lane];
  float xn1 = x[(size_t)n * 128 + 64 + lane] * scale[64 + lane] + shift[64 + lane];
  float2 w0 = *(const float2*)&W3[lane * 2];
  float2 w1 = *(const float2*)&W3[(64 + lane) * 2];
  float2 l0 = *(const float2*)&LW3[lane * 2];
  float2 l1 = *(const float2*)&LW3[(64 + lane) * 2];
  float hc0 = wsum(xn0 * w0.x + xn1 * w1.x);
  float hc1 = wsum(xn0 * w0.y + xn1 * w1.y);
  float lc0 = wsum(xn0 * l0.x + xn1 * l1.x);
  float lc1 = wsum(xn0 * l0.y + xn1 * l1.y);
  if (lane == 0) {
    h3[2 * n] = hc0; h3[2 * n + 1] = hc1;
    lin3[2 * n] = lc0; lin3[2 * n + 1] = lc1;
    es3[n] = hc0 * as3[0] + hc1 * as3[1];
    ed3[n] = hc0 * ad3[0] + hc1 * ad3[1];
  }
}

// ---------- layer 3 edge aggregation + final output (single sweep, no max) ----------
__global__ __launch_bounds__(256) void k_agg3(
    const int* __restrict__ rowptr, const int* __restrict__ col,
    const float* __restrict__ es, const float* __restrict__ ed,
    const float* __restrict__ h3, const float* __restrict__ lin3,
    const float* __restrict__ lb3, const float* __restrict__ gb3,
    float* __restrict__ out, int N) {
  int lane = threadIdx.x & 63;
  int d = blockIdx.x * 4 + (threadIdx.x >> 6);
  if (d >= N) return;
  int start = rowptr[d], end = rowptr[d + 1];
  float edd = ed[d];
  float ps = 0.f, a0 = 0.f, a1 = 0.f;
  for (int i = start + lane; i < end; i += 64) {
    int s = col[i];
    float e = es[s] + edd; e = e > 0.f ? e : LEAKY * e;
    float p = __expf(e);
    float2 hv = *(const float2*)&h3[2 * s];
    ps += p; a0 += p * hv.x; a1 += p * hv.y;
  }
  ps = wsum(ps); a0 = wsum(a0); a1 = wsum(a1);
  if (lane < 2) {
    float a = (lane == 0 ? a0 : a1) / ps;
    float v = lin3[2 * d + lane] + lb3[lane] + a + gb3[lane];
    out[2 * d + lane] = v > 0.f ? v : 0.f;
  }
}

extern "C" void kernel_launch(void* const* d_in, const int* in_sizes, int n_in,
                              void* d_out, int out_size, void* d_ws, size_t ws_size,
                              hipStream_t stream) {
  const float* x   = (const float*)d_in[0];
  const void*  ei  = d_in[1];
  const float* W1  = (const float*)d_in[2];
  const float* as1 = (const float*)d_in[3];
  const float* ad1 = (const float*)d_in[4];
  const float* gb1 = (const float*)d_in[5];
  const float* lw1 = (const float*)d_in[6];
  const float* lb1 = (const float*)d_in[7];
  const float* bg1 = (const float*)d_in[8];
  const float* bb1 = (const float*)d_in[9];
  const float* W2  = (const float*)d_in[10];
  const float* as2 = (const float*)d_in[11];
  const float* ad2 = (const float*)d_in[12];
  const float* gb2 = (const float*)d_in[13];
  const float* lw2 = (const float*)d_in[14];
  const float* lb2 = (const float*)d_in[15];
  const float* bg2 = (const float*)d_in[16];
  const float* bb2 = (const float*)d_in[17];
  const float* W3  = (const float*)d_in[18];
  const float* as3 = (const float*)d_in[19];
  const float* ad3 = (const float*)d_in[20];
  const float* gb3 = (const float*)d_in[21];
  const float* lw3 = (const float*)d_in[22];
  const float* lb3 = (const float*)d_in[23];
  const float* bg3 = (const float*)d_in[24];
  const float* bb3 = (const float*)d_in[25];
  float* out = (float*)d_out;

  int N = in_sizes[0] / 128;
  int E = in_sizes[1] / 2;

  char* wsp = (char*)d_ws;
  size_t off = 0;
  auto alloc = [&](size_t bytes) -> void* {
    void* p = wsp + off;
    off = (off + bytes + 255) & ~(size_t)255;
    return p;
  };
  int* flag    = (int*)alloc(4);
  int* deg     = (int*)alloc((size_t)N * 4);
  int* rowptr  = (int*)alloc(((size_t)N + 1) * 4);
  int* cursor  = (int*)alloc((size_t)N * 4);
  int* col     = (int*)alloc((size_t)(E + N) * 4);
  float* sums  = (float*)alloc(3 * 256 * 4);
  float* scl   = (float*)alloc(3 * 256 * 4);
  float* h     = (float*)alloc((size_t)N * 128 * 4);
  unsigned* hbp = (unsigned*)alloc((size_t)N * 64 * 4);  // packed-bf16 h
  float* lin   = (float*)alloc((size_t)N * 128 * 4);
  float* x2    = (float*)alloc((size_t)N * 128 * 4);
  float* es    = (float*)alloc((size_t)N * 2 * 4);
  float* edb   = (float*)alloc((size_t)N * 2 * 4);
  float* h3    = (float*)alloc((size_t)N * 2 * 4);
  float* lin3  = (float*)alloc((size_t)N * 2 * 4);
  float* es3   = (float*)alloc((size_t)N * 4);
  float* ed3   = (float*)alloc((size_t)N * 4);
  (void)ws_size; (void)n_in; (void)out_size;

  hipMemsetAsync(sums, 0, 3 * 256 * 4, stream);

  k_probe<<<1, 64, 0, stream>>>(ei, N, flag);
  k_deginit<<<(N + 255) / 256, 256, 0, stream>>>(deg, N);
  k_hist<<<(E + 255) / 256, 256, 0, stream>>>(ei, flag, E, deg);
  k_scan<<<1, 1024, 0, stream>>>(deg, N, rowptr, cursor);
  k_scatter<<<(E + N + 255) / 256, 256, 0, stream>>>(ei, flag, E, N, cursor, col);

  int gnode = (N + 3) / 4;
  int gmm = (N + MM_ROWS - 1) / MM_ROWS;

  // ---- layer 1 ----
  k_bnstats<<<1024, 128, 0, stream>>>(x, N, sums);
  k_bnfin<<<1, 128, 0, stream>>>(sums, bg1, bb1, N, scl, scl + 128);
  k_matmul<<<gmm, 256, 0, stream>>>(x, scl, scl + 128, W1, lw1, h, hbp, lin, N);
  k_esed<<<gnode, 256, 0, stream>>>(h, as1, ad1, es, edb, N);
  k_agg<<<gnode, 256, 0, stream>>>(rowptr, col, es, edb, hbp, lin, lb1, gb1, x2, N);

  // ---- layer 2 ----
  k_bnstats<<<1024, 128, 0, stream>>>(x2, N, sums + 256);
  k_bnfin<<<1, 128, 0, stream>>>(sums + 256, bg2, bb2, N, scl + 256, scl + 384);
  k_matmul<<<gmm, 256, 0, stream>>>(x2, scl + 256, scl + 384, W2, lw2, h, hbp, lin, N);
  k_esed<<<gnode, 256, 0, stream>>>(h, as2, ad2, es, edb, N);
  k_agg<<<gnode, 256, 0, stream>>>(rowptr, col, es, edb, hbp, lin, lb2, gb2, x2, N);

  // ---- layer 3 ----
  k_bnstats<<<1024, 128, 0, stream>>>(x2, N, sums + 512);
  k_bnfin<<<1, 128, 0, stream>>>(sums + 512, bg3, bb3, N, scl + 512, scl + 640);
  k_l3node<<<gnode, 256, 0, stream>>>(x2, scl + 512, scl + 640, W3, lw3, as3, ad3,
                                      h3, lin3, es3, ed3, N);
  k_agg3<<<gnode, 256, 0, stream>>>(rowptr, col, es3, ed3, h3, lin3, lb3, gb3, out, N);
}

// Round 3
// 700.971 us; speedup vs baseline: 1.6929x; 1.2680x over previous
//
#include <hip/hip_runtime.h>

#define LEAKY 0.2f
#define BN_EPS 1e-5f
#define BCHUNK 8192

// ---------- wave helpers (wave64) ----------
__device__ __forceinline__ float wsum(float v) {
#pragma unroll
  for (int o = 32; o > 0; o >>= 1) v += __shfl_xor(v, o, 64);
  return v;
}

// packed-bf16 decode: dword holds feat2j (low16) and feat2j+1 (high16)
__device__ __forceinline__ float blo(unsigned u) { return __uint_as_float(u << 16); }
__device__ __forceinline__ float bhi(unsigned u) { return __uint_as_float(u & 0xffff0000u); }
__device__ __forceinline__ unsigned pack_bf16(float a, float b) {
  unsigned ua = __float_as_uint(a), ub = __float_as_uint(b);
  ua = (ua + 0x7fffu + ((ua >> 16) & 1u)) >> 16;
  ub = (ub + 0x7fffu + ((ub >> 16) & 1u)) >> 16;
  return ua | (ub << 16);
}

// edge_index may be int64 (reference dtype) or int32 (JAX x64 disabled).
__device__ __forceinline__ int edge_at(const void* ei, int is64, long long i) {
  return is64 ? (int)((const long long*)ei)[i] : ((const int*)ei)[i];
}

// ---------- probe: detect int32 vs int64 edge_index ----------
__global__ void k_probe(const void* ei, int N, int* flag) {
  if (threadIdx.x == 0 && blockIdx.x == 0) {
    const long long* p = (const long long*)ei;
    int ok = 1;
    for (int i = 0; i < 64; ++i) {
      long long v = p[i];
      if (v < 0 || v >= (long long)N) { ok = 0; break; }
    }
    *flag = ok;  // 1 => int64 layout, 0 => int32 layout
  }
}

// ---------- CSR build: two-level counting sort (write-local) ----------
// Buckets = dst>>8 (nb = ceil(N/256) <= 1024 assumed). Edge stream index
// g in [0, M): g<E -> (src[g], dst[g]); g>=E -> self-loop (g-E, g-E).

// Pass A: per-chunk bucket histogram -> counts[bucket*nblk + chunk]
__global__ __launch_bounds__(256) void k_binA(const void* ei, const int* flag, int E, int M,
                                              int nb, int nblk, int* counts) {
  __shared__ int hist[1024];
  int tid = threadIdx.x;
  for (int j = tid; j < nb; j += 256) hist[j] = 0;
  __syncthreads();
  int is64 = *flag;
  long long base = (long long)blockIdx.x * BCHUNK;
  int cnt = (int)min((long long)BCHUNK, (long long)M - base);
  for (int i = tid; i < cnt; i += 256) {
    long long g = base + i;
    int d = (g < E) ? edge_at(ei, is64, (long long)E + g) : (int)(g - E);
    atomicAdd(&hist[d >> 8], 1);
  }
  __syncthreads();
  for (int j = tid; j < nb; j += 256) counts[(size_t)j * nblk + blockIdx.x] = hist[j];
}

// Pass B: flat exclusive scan over counts (bucket-major => global offsets)
__global__ __launch_bounds__(1024) void k_binScan(int* counts, int total_entries) {
  __shared__ int part[1024];
  int tid = threadIdx.x;
  int per = (total_entries + 1023) / 1024;
  int lo = tid * per;
  int hi = lo + per; if (hi > total_entries) hi = total_entries;
  int s = 0;
  for (int i = lo; i < hi; ++i) s += counts[i];
  part[tid] = s;
  __syncthreads();
  for (int off = 1; off < 1024; off <<= 1) {
    int add = (tid >= off) ? part[tid - off] : 0;
    __syncthreads();
    part[tid] += add;
    __syncthreads();
  }
  int run = (tid == 0) ? 0 : part[tid - 1];
  for (int i = lo; i < hi; ++i) {
    int c = counts[i];
    counts[i] = run;
    run += c;
  }
}

// Pass C: scatter packed (src<<8 | dst&255) into bucket-partitioned tmp.
// Each block's writes per bucket are contiguous runs -> low write amplification.
__global__ __launch_bounds__(256) void k_binC(const void* ei, const int* flag, int E, int M,
                                              int nb, int nblk, const int* counts, unsigned* tmp) {
  __shared__ int cur[1024];
  int tid = threadIdx.x;
  for (int j = tid; j < nb; j += 256) cur[j] = counts[(size_t)j * nblk + blockIdx.x];
  __syncthreads();
  int is64 = *flag;
  long long base = (long long)blockIdx.x * BCHUNK;
  int cnt = (int)min((long long)BCHUNK, (long long)M - base);
  for (int i = tid; i < cnt; i += 256) {
    long long g = base + i;
    int s, d;
    if (g < E) { s = edge_at(ei, is64, g); d = edge_at(ei, is64, (long long)E + g); }
    else       { s = d = (int)(g - E); }
    int pos = atomicAdd(&cur[d >> 8], 1);
    tmp[pos] = ((unsigned)s << 8) | (unsigned)(d & 255);
  }
}

// Pass D: per-bucket counting sort -> rowptr + col. Writes stay in a ~34KB
// contiguous col window (L2-local).
__global__ __launch_bounds__(256) void k_binD(const unsigned* __restrict__ tmp,
                                              const int* __restrict__ counts,
                                              int nb, int nblk, int M, int N,
                                              int* __restrict__ rowptr, int* __restrict__ col) {
  __shared__ int scn[256];
  __shared__ int cur[256];
  int tid = threadIdx.x;
  int j = blockIdx.x;
  int base = counts[(size_t)j * nblk];
  int endv = (j + 1 < nb) ? counts[(size_t)(j + 1) * nblk] : M;
  int bc = endv - base;
  scn[tid] = 0;
  __syncthreads();
  for (int i = tid; i < bc; i += 256) atomicAdd(&scn[tmp[base + i] & 255], 1);
  __syncthreads();
  int v = scn[tid];
  __syncthreads();
  scn[tid] = v;
  __syncthreads();
  for (int off = 1; off < 256; off <<= 1) {
    int add = (tid >= off) ? scn[tid - off] : 0;
    __syncthreads();
    scn[tid] += add;
    __syncthreads();
  }
  int excl = scn[tid] - v;  // exclusive prefix within bucket
  int d = (j << 8) + tid;
  if (d < N) rowptr[d] = base + excl;
  cur[tid] = base + excl;
  __syncthreads();
  for (int i = tid; i < bc; i += 256) {
    unsigned w = tmp[base + i];
    int pos = atomicAdd(&cur[w & 255], 1);
    col[pos] = (int)(w >> 8);
  }
  if (j == nb - 1 && tid == 0) rowptr[N] = M;
}

// ---------- BatchNorm stats ----------
__global__ __launch_bounds__(128) void k_bnstats(const float* __restrict__ x, int N, float* sums) {
  int f = threadIdx.x;  // 128 features
  float s = 0.f, s2 = 0.f;
  for (int r = blockIdx.x; r < N; r += gridDim.x) {
    float v = x[(size_t)r * 128 + f];
    s += v; s2 += v * v;
  }
  atomicAdd(&sums[f], s);
  atomicAdd(&sums[128 + f], s2);
}

__global__ void k_bnfin(const float* sums, const float* __restrict__ gamma,
                        const float* __restrict__ beta, int N, float* scale, float* shift) {
  int f = threadIdx.x;  // 128
  float inv_n = 1.0f / (float)N;
  float mu = sums[f] * inv_n;
  float var = sums[128 + f] * inv_n - mu * mu;
  float rs = rsqrtf(var + BN_EPS);
  float sc = gamma[f] * rs;
  scale[f] = sc;
  shift[f] = beta[f] - mu * sc;
}

// ---------- fused BN-apply + dual matmul: [h | lin] = xn @ [W | LW] ----------
#define MM_ROWS 32
__global__ __launch_bounds__(256) void k_matmul(
    const float* __restrict__ x, const float* __restrict__ scale, const float* __restrict__ shift,
    const float* __restrict__ W, const float* __restrict__ LW,
    float* __restrict__ h, unsigned* __restrict__ hb, float* __restrict__ lin, int N) {
  __shared__ __align__(16) float xrow[MM_ROWS][132];  // +4 pad
  __shared__ __align__(16) float wbuf[32][256];       // k-chunk of [W|LW]
  int tid = threadIdx.x;
  int tx = tid & 63;   // col quad: cols 4*tx..4*tx+3
  int ty = tid >> 6;   // 0..3: rows ty*8..ty*8+7
  int rowBase = blockIdx.x * MM_ROWS;

  for (int q = tid; q < MM_ROWS * 32; q += 256) {
    int r = q >> 5, kq = q & 31;
    int row = rowBase + r;
    float4 v = make_float4(0.f, 0.f, 0.f, 0.f);
    if (row < N) v = *(const float4*)&x[(size_t)row * 128 + kq * 4];
    float4 sc = *(const float4*)&scale[kq * 4];
    float4 sh = *(const float4*)&shift[kq * 4];
    float4 o;
    o.x = v.x * sc.x + sh.x; o.y = v.y * sc.y + sh.y;
    o.z = v.z * sc.z + sh.z; o.w = v.w * sc.w + sh.w;
    *(float4*)&xrow[r][kq * 4] = o;
  }

  float acc[8][4];
#pragma unroll
  for (int r = 0; r < 8; ++r)
#pragma unroll
    for (int c = 0; c < 4; ++c) acc[r][c] = 0.f;

  for (int kc = 0; kc < 4; ++kc) {
    __syncthreads();
    for (int q = tid; q < 32 * 64; q += 256) {
      int kk = q >> 6, cq = q & 63;
      int k = kc * 32 + kk, c = cq * 4;
      float4 wv;
      if (c < 128) wv = *(const float4*)&W[(size_t)k * 128 + c];
      else         wv = *(const float4*)&LW[(size_t)k * 128 + (c - 128)];
      *(float4*)&wbuf[kk][c] = wv;
    }
    __syncthreads();
#pragma unroll
    for (int k4 = 0; k4 < 8; ++k4) {
      float4 w0 = *(const float4*)&wbuf[k4 * 4 + 0][tx * 4];
      float4 w1 = *(const float4*)&wbuf[k4 * 4 + 1][tx * 4];
      float4 w2 = *(const float4*)&wbuf[k4 * 4 + 2][tx * 4];
      float4 w3 = *(const float4*)&wbuf[k4 * 4 + 3][tx * 4];
#pragma unroll
      for (int r = 0; r < 8; ++r) {
        float4 xv = *(const float4*)&xrow[ty * 8 + r][kc * 32 + k4 * 4];
        acc[r][0] += xv.x * w0.x + xv.y * w1.x + xv.z * w2.x + xv.w * w3.x;
        acc[r][1] += xv.x * w0.y + xv.y * w1.y + xv.z * w2.y + xv.w * w3.y;
        acc[r][2] += xv.x * w0.z + xv.y * w1.z + xv.z * w2.z + xv.w * w3.z;
        acc[r][3] += xv.x * w0.w + xv.y * w1.w + xv.z * w2.w + xv.w * w3.w;
      }
    }
  }
#pragma unroll
  for (int r = 0; r < 8; ++r) {
    int row = rowBase + ty * 8 + r;
    if (row >= N) continue;
    float4 v = make_float4(acc[r][0], acc[r][1], acc[r][2], acc[r][3]);
    int c = tx * 4;
    if (c < 128) {
      *(float4*)&h[(size_t)row * 128 + c] = v;
      uint2 pk;
      pk.x = pack_bf16(v.x, v.y);
      pk.y = pack_bf16(v.z, v.w);
      *(uint2*)&hb[(size_t)row * 64 + (c >> 1)] = pk;
    } else {
      *(float4*)&lin[(size_t)row * 128 + (c - 128)] = v;
    }
  }
}

// ---------- es/ed per node (2 heads, 64 feats each) ----------
__global__ __launch_bounds__(256) void k_esed(const float* __restrict__ h,
                                              const float* __restrict__ as_, const float* __restrict__ ad_,
                                              float* es, float* ed, int N) {
  int lane = threadIdx.x & 63;
  int n = blockIdx.x * 4 + (threadIdx.x >> 6);
  if (n >= N) return;
  float h0 = h[(size_t)n * 128 + lane];
  float h1 = h[(size_t)n * 128 + 64 + lane];
  float e0 = wsum(h0 * as_[lane]);
  float e1 = wsum(h1 * as_[64 + lane]);
  float d0 = wsum(h0 * ad_[lane]);
  float d1 = wsum(h1 * ad_[64 + lane]);
  if (lane == 0) {
    es[2 * n] = e0; es[2 * n + 1] = e1;
    ed[2 * n] = d0; ed[2 * n + 1] = d1;
  }
}

// ---------- edge aggregation + combine (layers 1&2); one wave per dst ----------
__global__ __launch_bounds__(256) void k_agg(
    const int* __restrict__ rowptr, const int* __restrict__ col,
    const float* __restrict__ es, const float* __restrict__ ed,
    const unsigned* __restrict__ hb, const float* __restrict__ lin,
    const float* __restrict__ lb, const float* __restrict__ gb,
    float* __restrict__ xout, int N) {
  __shared__ float2 pbuf[4][128];
  int lane = threadIdx.x & 63;
  int w = threadIdx.x >> 6;
  int d = blockIdx.x * 4 + w;
  if (d >= N) return;
  int start = rowptr[d], end = rowptr[d + 1];
  float2 edv = *(const float2*)&ed[2 * d];
  int head_hi = lane >= 32;

  // pass A: exp weights (edge-parallel), cache first 128 in LDS, sum
  float s0 = 0.f, s1 = 0.f;
  for (int i = start + lane; i < end; i += 64) {
    int s = col[i];
    float2 ev = *(const float2*)&es[2 * s];
    float e0 = ev.x + edv.x; e0 = e0 > 0.f ? e0 : LEAKY * e0;
    float e1 = ev.y + edv.y; e1 = e1 > 0.f ? e1 : LEAKY * e1;
    float p0 = __expf(e0), p1 = __expf(e1);
    int j = i - start;
    if (j < 128) pbuf[w][j] = make_float2(p0, p1);
    s0 += p0; s1 += p1;
  }
  s0 = wsum(s0); s1 = wsum(s1);
  float inv = 1.0f / (head_hi ? s1 : s0);

  // pass B: weighted gather, feature-parallel (lane -> feats 2*lane, 2*lane+1)
  float acc0 = 0.f, acc1 = 0.f;
  int bounded = end < start + 128 ? end : start + 128;
  int i = start;
  for (; i + 4 <= bounded; i += 4) {
    int j = i - start;
    int c0 = col[i], c1 = col[i + 1], c2 = col[i + 2], c3 = col[i + 3];
    float2 w0 = pbuf[w][j], w1 = pbuf[w][j + 1], w2 = pbuf[w][j + 2], w3 = pbuf[w][j + 3];
    unsigned u0 = hb[(size_t)c0 * 64 + lane];
    unsigned u1 = hb[(size_t)c1 * 64 + lane];
    unsigned u2 = hb[(size_t)c2 * 64 + lane];
    unsigned u3 = hb[(size_t)c3 * 64 + lane];
    float f0 = head_hi ? w0.y : w0.x;
    float f1 = head_hi ? w1.y : w1.x;
    float f2 = head_hi ? w2.y : w2.x;
    float f3 = head_hi ? w3.y : w3.x;
    acc0 = fmaf(f0, blo(u0), acc0); acc1 = fmaf(f0, bhi(u0), acc1);
    acc0 = fmaf(f1, blo(u1), acc0); acc1 = fmaf(f1, bhi(u1), acc1);
    acc0 = fmaf(f2, blo(u2), acc0); acc1 = fmaf(f2, bhi(u2), acc1);
    acc0 = fmaf(f3, blo(u3), acc0); acc1 = fmaf(f3, bhi(u3), acc1);
  }
  for (; i < bounded; ++i) {
    int j = i - start;
    int c0 = col[i];
    float2 w0 = pbuf[w][j];
    unsigned u0 = hb[(size_t)c0 * 64 + lane];
    float f0 = head_hi ? w0.y : w0.x;
    acc0 = fmaf(f0, blo(u0), acc0); acc1 = fmaf(f0, bhi(u0), acc1);
  }
  for (; i < end; ++i) {  // deg > 128 slow path (recompute weight)
    int s = col[i];
    float2 ev = *(const float2*)&es[2 * s];
    float e0 = ev.x + edv.x; e0 = e0 > 0.f ? e0 : LEAKY * e0;
    float e1 = ev.y + edv.y; e1 = e1 > 0.f ? e1 : LEAKY * e1;
    float p0 = __expf(e0), p1 = __expf(e1);
    float f0 = head_hi ? p1 : p0;
    unsigned u0 = hb[(size_t)s * 64 + lane];
    acc0 = fmaf(f0, blo(u0), acc0); acc1 = fmaf(f0, bhi(u0), acc1);
  }

  // epilogue: feats f=2*lane, f+1
  int f = 2 * lane;
  size_t b = (size_t)d * 128 + f;
  float2 lv = *(const float2*)&lin[b];
  float2 lbv = *(const float2*)&lb[f];
  float2 gbv = *(const float2*)&gb[f];
  float v0 = lv.x + lbv.x + acc0 * inv + gbv.x;
  float v1 = lv.y + lbv.y + acc1 * inv + gbv.y;
  float2 o; o.x = v0 > 0.f ? v0 : 0.f; o.y = v1 > 0.f ? v1 : 0.f;
  *(float2*)&xout[b] = o;
}

// ---------- layer 3: BN-apply + tiny matmul + es/ed (1 head, 2 out feats) ----------
__global__ __launch_bounds__(256) void k_l3node(
    const float* __restrict__ x, const float* __restrict__ scale, const float* __restrict__ shift,
    const float* __restrict__ W3, const float* __restrict__ LW3,
    const float* __restrict__ as3, const float* __restrict__ ad3,
    float* h3, float* lin3, float* es3, float* ed3, int N) {
  int lane = threadIdx.x & 63;
  int n = blockIdx.x * 4 + (threadIdx.x >> 6);
  if (n >= N) return;
  float xn0 = x[(size_t)n * 128 + lane] * scale[lane] + shift[lane];
  float xn1 = x[(size_t)n * 128 + 64 + lane] * scale[64 + lane] + shift[64 + lane];
  float2 w0 = *(const float2*)&W3[lane * 2];
  float2 w1 = *(const float2*)&W3[(64 + lane) * 2];
  float2 l0 = *(const float2*)&LW3[lane * 2];
  float2 l1 = *(const float2*)&LW3[(64 + lane) * 2];
  float hc0 = wsum(xn0 * w0.x + xn1 * w1.x);
  float hc1 = wsum(xn0 * w0.y + xn1 * w1.y);
  float lc0 = wsum(xn0 * l0.x + xn1 * l1.x);
  float lc1 = wsum(xn0 * l0.y + xn1 * l1.y);
  if (lane == 0) {
    h3[2 * n] = hc0; h3[2 * n + 1] = hc1;
    lin3[2 * n] = lc0; lin3[2 * n + 1] = lc1;
    es3[n] = hc0 * as3[0] + hc1 * as3[1];
    ed3[n] = hc0 * ad3[0] + hc1 * ad3[1];
  }
}

// ---------- layer 3 edge aggregation + final output (single sweep, no max) ----------
__global__ __launch_bounds__(256) void k_agg3(
    const int* __restrict__ rowptr, const int* __restrict__ col,
    const float* __restrict__ es, const float* __restrict__ ed,
    const float* __restrict__ h3, const float* __restrict__ lin3,
    const float* __restrict__ lb3, const float* __restrict__ gb3,
    float* __restrict__ out, int N) {
  int lane = threadIdx.x & 63;
  int d = blockIdx.x * 4 + (threadIdx.x >> 6);
  if (d >= N) return;
  int start = rowptr[d], end = rowptr[d + 1];
  float edd = ed[d];
  float ps = 0.f, a0 = 0.f, a1 = 0.f;
  for (int i = start + lane; i < end; i += 64) {
    int s = col[i];
    float e = es[s] + edd; e = e > 0.f ? e : LEAKY * e;
    float p = __expf(e);
    float2 hv = *(const float2*)&h3[2 * s];
    ps += p; a0 += p * hv.x; a1 += p * hv.y;
  }
  ps = wsum(ps); a0 = wsum(a0); a1 = wsum(a1);
  if (lane < 2) {
    float a = (lane == 0 ? a0 : a1) / ps;
    float v = lin3[2 * d + lane] + lb3[lane] + a + gb3[lane];
    out[2 * d + lane] = v > 0.f ? v : 0.f;
  }
}

extern "C" void kernel_launch(void* const* d_in, const int* in_sizes, int n_in,
                              void* d_out, int out_size, void* d_ws, size_t ws_size,
                              hipStream_t stream) {
  const float* x   = (const float*)d_in[0];
  const void*  ei  = d_in[1];
  const float* W1  = (const float*)d_in[2];
  const float* as1 = (const float*)d_in[3];
  const float* ad1 = (const float*)d_in[4];
  const float* gb1 = (const float*)d_in[5];
  const float* lw1 = (const float*)d_in[6];
  const float* lb1 = (const float*)d_in[7];
  const float* bg1 = (const float*)d_in[8];
  const float* bb1 = (const float*)d_in[9];
  const float* W2  = (const float*)d_in[10];
  const float* as2 = (const float*)d_in[11];
  const float* ad2 = (const float*)d_in[12];
  const float* gb2 = (const float*)d_in[13];
  const float* lw2 = (const float*)d_in[14];
  const float* lb2 = (const float*)d_in[15];
  const float* bg2 = (const float*)d_in[16];
  const float* bb2 = (const float*)d_in[17];
  const float* W3  = (const float*)d_in[18];
  const float* as3 = (const float*)d_in[19];
  const float* ad3 = (const float*)d_in[20];
  const float* gb3 = (const float*)d_in[21];
  const float* lw3 = (const float*)d_in[22];
  const float* lb3 = (const float*)d_in[23];
  const float* bg3 = (const float*)d_in[24];
  const float* bb3 = (const float*)d_in[25];
  float* out = (float*)d_out;

  int N = in_sizes[0] / 128;
  int E = in_sizes[1] / 2;
  int M = E + N;                      // edges + self-loops
  int nb = (N + 255) >> 8;            // coarse buckets (dst>>8), <=1024
  int nblk = (M + BCHUNK - 1) / BCHUNK;

  char* wsp = (char*)d_ws;
  size_t off = 0;
  auto alloc = [&](size_t bytes) -> void* {
    void* p = wsp + off;
    off = (off + bytes + 255) & ~(size_t)255;
    return p;
  };
  int* flag     = (int*)alloc(4);
  int* rowptr   = (int*)alloc(((size_t)N + 1) * 4);
  int* col      = (int*)alloc((size_t)M * 4);
  unsigned* tmp = (unsigned*)alloc((size_t)M * 4);
  int* counts   = (int*)alloc(((size_t)nb * nblk + 1) * 4);
  float* sums  = (float*)alloc(3 * 256 * 4);
  float* scl   = (float*)alloc(3 * 256 * 4);
  float* h     = (float*)alloc((size_t)N * 128 * 4);
  unsigned* hbp = (unsigned*)alloc((size_t)N * 64 * 4);  // packed-bf16 h
  float* lin   = (float*)alloc((size_t)N * 128 * 4);
  float* x2    = (float*)alloc((size_t)N * 128 * 4);
  float* es    = (float*)alloc((size_t)N * 2 * 4);
  float* edb   = (float*)alloc((size_t)N * 2 * 4);
  float* h3    = (float*)alloc((size_t)N * 2 * 4);
  float* lin3  = (float*)alloc((size_t)N * 2 * 4);
  float* es3   = (float*)alloc((size_t)N * 4);
  float* ed3   = (float*)alloc((size_t)N * 4);
  (void)ws_size; (void)n_in; (void)out_size;

  hipMemsetAsync(sums, 0, 3 * 256 * 4, stream);

  // CSR build via bucketed counting sort (shared across all 3 layers)
  k_probe<<<1, 64, 0, stream>>>(ei, N, flag);
  k_binA<<<nblk, 256, 0, stream>>>(ei, flag, E, M, nb, nblk, counts);
  k_binScan<<<1, 1024, 0, stream>>>(counts, nb * nblk);
  k_binC<<<nblk, 256, 0, stream>>>(ei, flag, E, M, nb, nblk, counts, tmp);
  k_binD<<<nb, 256, 0, stream>>>(tmp, counts, nb, nblk, M, N, rowptr, col);

  int gnode = (N + 3) / 4;
  int gmm = (N + MM_ROWS - 1) / MM_ROWS;

  // ---- layer 1 ----
  k_bnstats<<<1024, 128, 0, stream>>>(x, N, sums);
  k_bnfin<<<1, 128, 0, stream>>>(sums, bg1, bb1, N, scl, scl + 128);
  k_matmul<<<gmm, 256, 0, stream>>>(x, scl, scl + 128, W1, lw1, h, hbp, lin, N);
  k_esed<<<gnode, 256, 0, stream>>>(h, as1, ad1, es, edb, N);
  k_agg<<<gnode, 256, 0, stream>>>(rowptr, col, es, edb, hbp, lin, lb1, gb1, x2, N);

  // ---- layer 2 ----
  k_bnstats<<<1024, 128, 0, stream>>>(x2, N, sums + 256);
  k_bnfin<<<1, 128, 0, stream>>>(sums + 256, bg2, bb2, N, scl + 256, scl + 384);
  k_matmul<<<gmm, 256, 0, stream>>>(x2, scl + 256, scl + 384, W2, lw2, h, hbp, lin, N);
  k_esed<<<gnode, 256, 0, stream>>>(h, as2, ad2, es, edb, N);
  k_agg<<<gnode, 256, 0, stream>>>(rowptr, col, es, edb, hbp, lin, lb2, gb2, x2, N);

  // ---- layer 3 ----
  k_bnstats<<<1024, 128, 0, stream>>>(x2, N, sums + 512);
  k_bnfin<<<1, 128, 0, stream>>>(sums + 512, bg3, bb3, N, scl + 512, scl + 640);
  k_l3node<<<gnode, 256, 0, stream>>>(x2, scl + 512, scl + 640, W3, lw3, as3, ad3,
                                      h3, lin3, es3, ed3, N);
  k_agg3<<<gnode, 256, 0, stream>>>(rowptr, col, es3, ed3, h3, lin3, lb3, gb3, out, N);
}

// Round 4
// 582.598 us; speedup vs baseline: 2.0368x; 1.2032x over previous
//
#include <hip/hip_runtime.h>

#define LEAKY 0.2f
#define BN_EPS 1e-5f
#define BCHUNK 8192

typedef __bf16 v8bf __attribute__((ext_vector_type(8)));
typedef float v16f __attribute__((ext_vector_type(16)));

// ---------- wave helpers (wave64) ----------
__device__ __forceinline__ float wsum(float v) {
#pragma unroll
  for (int o = 32; o > 0; o >>= 1) v += __shfl_xor(v, o, 64);
  return v;
}

// packed-bf16 decode: dword holds feat2j (low16) and feat2j+1 (high16)
__device__ __forceinline__ float blo(unsigned u) { return __uint_as_float(u << 16); }
__device__ __forceinline__ float bhi(unsigned u) { return __uint_as_float(u & 0xffff0000u); }
__device__ __forceinline__ unsigned pack_bf16(float a, float b) {
  unsigned ua = __float_as_uint(a), ub = __float_as_uint(b);
  ua = (ua + 0x7fffu + ((ua >> 16) & 1u)) >> 16;
  ub = (ub + 0x7fffu + ((ub >> 16) & 1u)) >> 16;
  return ua | (ub << 16);
}
__device__ __forceinline__ unsigned short bf16of(float a) {
  unsigned ua = __float_as_uint(a);
  return (unsigned short)((ua + 0x7fffu + ((ua >> 16) & 1u)) >> 16);
}

// edge_index may be int64 (reference dtype) or int32 (JAX x64 disabled).
__device__ __forceinline__ int edge_at(const void* ei, int is64, long long i) {
  return is64 ? (int)((const long long*)ei)[i] : ((const int*)ei)[i];
}

// ---------- probe: detect int32 vs int64 edge_index ----------
__global__ void k_probe(const void* ei, int N, int* flag) {
  if (threadIdx.x == 0 && blockIdx.x == 0) {
    const long long* p = (const long long*)ei;
    int ok = 1;
    for (int i = 0; i < 64; ++i) {
      long long v = p[i];
      if (v < 0 || v >= (long long)N) { ok = 0; break; }
    }
    *flag = ok;  // 1 => int64 layout, 0 => int32 layout
  }
}

// ---------- CSR build: two-level counting sort (write-local) ----------
__global__ __launch_bounds__(256) void k_binA(const void* ei, const int* flag, int E, int M,
                                              int nb, int nblk, int* counts) {
  __shared__ int hist[1024];
  int tid = threadIdx.x;
  for (int j = tid; j < nb; j += 256) hist[j] = 0;
  __syncthreads();
  int is64 = *flag;
  long long base = (long long)blockIdx.x * BCHUNK;
  int cnt = (int)min((long long)BCHUNK, (long long)M - base);
  for (int i = tid; i < cnt; i += 256) {
    long long g = base + i;
    int d = (g < E) ? edge_at(ei, is64, (long long)E + g) : (int)(g - E);
    atomicAdd(&hist[d >> 8], 1);
  }
  __syncthreads();
  for (int j = tid; j < nb; j += 256) counts[(size_t)j * nblk + blockIdx.x] = hist[j];
}

__global__ __launch_bounds__(1024) void k_binScan(int* counts, int total_entries) {
  __shared__ int part[1024];
  int tid = threadIdx.x;
  int per = (total_entries + 1023) / 1024;
  int lo = tid * per;
  int hi = lo + per; if (hi > total_entries) hi = total_entries;
  int s = 0;
  for (int i = lo; i < hi; ++i) s += counts[i];
  part[tid] = s;
  __syncthreads();
  for (int off = 1; off < 1024; off <<= 1) {
    int add = (tid >= off) ? part[tid - off] : 0;
    __syncthreads();
    part[tid] += add;
    __syncthreads();
  }
  int run = (tid == 0) ? 0 : part[tid - 1];
  for (int i = lo; i < hi; ++i) {
    int c = counts[i];
    counts[i] = run;
    run += c;
  }
}

__global__ __launch_bounds__(256) void k_binC(const void* ei, const int* flag, int E, int M,
                                              int nb, int nblk, const int* counts, unsigned* tmp) {
  __shared__ int cur[1024];
  int tid = threadIdx.x;
  for (int j = tid; j < nb; j += 256) cur[j] = counts[(size_t)j * nblk + blockIdx.x];
  __syncthreads();
  int is64 = *flag;
  long long base = (long long)blockIdx.x * BCHUNK;
  int cnt = (int)min((long long)BCHUNK, (long long)M - base);
  for (int i = tid; i < cnt; i += 256) {
    long long g = base + i;
    int s, d;
    if (g < E) { s = edge_at(ei, is64, g); d = edge_at(ei, is64, (long long)E + g); }
    else       { s = d = (int)(g - E); }
    int pos = atomicAdd(&cur[d >> 8], 1);
    tmp[pos] = ((unsigned)s << 8) | (unsigned)(d & 255);
  }
}

__global__ __launch_bounds__(256) void k_binD(const unsigned* __restrict__ tmp,
                                              const int* __restrict__ counts,
                                              int nb, int nblk, int M, int N,
                                              int* __restrict__ rowptr, int* __restrict__ col) {
  __shared__ int scn[256];
  __shared__ int cur[256];
  int tid = threadIdx.x;
  int j = blockIdx.x;
  int base = counts[(size_t)j * nblk];
  int endv = (j + 1 < nb) ? counts[(size_t)(j + 1) * nblk] : M;
  int bc = endv - base;
  scn[tid] = 0;
  __syncthreads();
  for (int i = tid; i < bc; i += 256) atomicAdd(&scn[tmp[base + i] & 255], 1);
  __syncthreads();
  int v = scn[tid];
  __syncthreads();
  scn[tid] = v;
  __syncthreads();
  for (int off = 1; off < 256; off <<= 1) {
    int add = (tid >= off) ? scn[tid - off] : 0;
    __syncthreads();
    scn[tid] += add;
    __syncthreads();
  }
  int excl = scn[tid] - v;
  int d = (j << 8) + tid;
  if (d < N) rowptr[d] = base + excl;
  cur[tid] = base + excl;
  __syncthreads();
  for (int i = tid; i < bc; i += 256) {
    unsigned w = tmp[base + i];
    int pos = atomicAdd(&cur[w & 255], 1);
    col[pos] = (int)(w >> 8);
  }
  if (j == nb - 1 && tid == 0) rowptr[N] = M;
}

// ---------- BatchNorm stats ----------
__global__ __launch_bounds__(128) void k_bnstats(const float* __restrict__ x, int N, float* sums) {
  int f = threadIdx.x;
  float s = 0.f, s2 = 0.f;
  for (int r = blockIdx.x; r < N; r += gridDim.x) {
    float v = x[(size_t)r * 128 + f];
    s += v; s2 += v * v;
  }
  atomicAdd(&sums[f], s);
  atomicAdd(&sums[128 + f], s2);
}

__global__ void k_bnfin(const float* sums, const float* __restrict__ gamma,
                        const float* __restrict__ beta, int N, float* scale, float* shift) {
  int f = threadIdx.x;
  float inv_n = 1.0f / (float)N;
  float mu = sums[f] * inv_n;
  float var = sums[128 + f] * inv_n - mu * mu;
  float rs = rsqrtf(var + BN_EPS);
  float sc = gamma[f] * rs;
  scale[f] = sc;
  shift[f] = beta[f] - mu * sc;
}

// ---------- B-prep: [W|LW] fp32 -> fragment-ordered bf16 ----------
// frag fi = (tile*8 + kstep)*64 + lane; tile in [0,8): cols 32t..32t+31.
// lane holds B[k0+j][n], n = 32t + (lane&31), k0 = kstep*16 + (lane>>5)*8.
__global__ __launch_bounds__(256) void k_prepB(const float* __restrict__ W,
                                               const float* __restrict__ LW,
                                               unsigned short* __restrict__ Bp) {
  int fi = blockIdx.x * 256 + threadIdx.x;  // 4096 frags
  int lane = fi & 63, s = (fi >> 6) & 7, t = fi >> 9;
  int n = t * 32 + (lane & 31);
  int k0 = s * 16 + (lane >> 5) * 8;
  unsigned short tmp[8];
#pragma unroll
  for (int j = 0; j < 8; ++j) {
    int k = k0 + j;
    float v = (n < 128) ? W[k * 128 + n] : LW[k * 128 + (n - 128)];
    tmp[j] = bf16of(v);
  }
  uint4 pk;
  pk.x = (unsigned)tmp[0] | ((unsigned)tmp[1] << 16);
  pk.y = (unsigned)tmp[2] | ((unsigned)tmp[3] << 16);
  pk.z = (unsigned)tmp[4] | ((unsigned)tmp[5] << 16);
  pk.w = (unsigned)tmp[6] | ((unsigned)tmp[7] << 16);
  *(uint4*)&Bp[(size_t)fi * 8] = pk;
}

// ---------- MFMA matmul: [hb | lin] = bf16(BN(x)) @ [W | LW] ----------
// Block: 32 rows x 256 cols, 4 waves; wave w owns col tiles 2w, 2w+1.
// v_mfma_f32_32x32x16_bf16: A[m=lane&31][k=(lane>>5)*8+j]; C/D col=lane&31,
// row=(reg&3)+8*(reg>>2)+4*(lane>>5).
__global__ __launch_bounds__(256) void k_mm(
    const float* __restrict__ x, const float* __restrict__ scale, const float* __restrict__ shift,
    const unsigned short* __restrict__ Bp,
    unsigned* __restrict__ hb, float* __restrict__ lin, int N) {
  __shared__ __align__(16) unsigned short Al[32 * 136];  // 32 rows, 128 + 8 pad bf16
  int tid = threadIdx.x;
  int lane = tid & 63;
  int w = tid >> 6;
  int rowBase = blockIdx.x * 32;

  // B fragments: 2 tiles x 8 k-steps, registers (L2-hot, fully coalesced 16B)
  v8bf bfrag[2][8];
#pragma unroll
  for (int t = 0; t < 2; ++t)
#pragma unroll
    for (int s = 0; s < 8; ++s) {
      int fi = ((2 * w + t) * 8 + s) * 64 + lane;
      bfrag[t][s] = *(const v8bf*)&Bp[(size_t)fi * 8];
    }

  // stage A with BN affine, fp32 -> bf16
  for (int q = tid; q < 32 * 32; q += 256) {
    int r = q >> 5, k4 = (q & 31) * 4;
    int row = rowBase + r;
    float4 v = make_float4(0.f, 0.f, 0.f, 0.f);
    if (row < N) v = *(const float4*)&x[(size_t)row * 128 + k4];
    float4 sc = *(const float4*)&scale[k4];
    float4 sh = *(const float4*)&shift[k4];
    unsigned p0 = pack_bf16(v.x * sc.x + sh.x, v.y * sc.y + sh.y);
    unsigned p1 = pack_bf16(v.z * sc.z + sh.z, v.w * sc.w + sh.w);
    *(uint2*)&Al[r * 136 + k4] = make_uint2(p0, p1);
  }
  __syncthreads();

  int m = lane & 31, half = lane >> 5;
  v8bf afrag[8];
#pragma unroll
  for (int s = 0; s < 8; ++s)
    afrag[s] = *(const v8bf*)&Al[m * 136 + s * 16 + half * 8];

  v16f acc0 = {}, acc1 = {};
#pragma unroll
  for (int s = 0; s < 8; ++s) {
    acc0 = __builtin_amdgcn_mfma_f32_32x32x16_bf16(afrag[s], bfrag[0][s], acc0, 0, 0, 0);
    acc1 = __builtin_amdgcn_mfma_f32_32x32x16_bf16(afrag[s], bfrag[1][s], acc1, 0, 0, 0);
  }

  // epilogue: waves 0,1 -> hb (packed bf16, pair cols via shfl); waves 2,3 -> lin fp32
  int mlo = half * 4;
  int t0 = 2 * w, t1 = 2 * w + 1;
#pragma unroll
  for (int r = 0; r < 16; ++r) {
    int row = (r & 3) + 8 * (r >> 2) + mlo;
    int node = rowBase + row;
    float a0 = acc0[r], a1 = acc1[r];
    float b0 = __shfl_xor(a0, 1, 64);
    float b1 = __shfl_xor(a1, 1, 64);
    if (node >= N) continue;
    if (t0 < 4) {
      if (!(lane & 1)) {
        int c0 = t0 * 32 + m, c1 = t1 * 32 + m;
        hb[(size_t)node * 64 + (c0 >> 1)] = pack_bf16(a0, b0);
        hb[(size_t)node * 64 + (c1 >> 1)] = pack_bf16(a1, b1);
      }
    } else {
      int c0 = t0 * 32 + m - 128, c1 = t1 * 32 + m - 128;
      lin[(size_t)node * 128 + c0] = a0;
      lin[(size_t)node * 128 + c1] = a1;
    }
  }
}

// ---------- es/ed per node from packed-bf16 hb ----------
__global__ __launch_bounds__(256) void k_esed(const unsigned* __restrict__ hb,
                                              const float* __restrict__ as_, const float* __restrict__ ad_,
                                              float* es, float* ed, int N) {
  int lane = threadIdx.x & 63;
  int n = blockIdx.x * 4 + (threadIdx.x >> 6);
  if (n >= N) return;
  unsigned u = hb[(size_t)n * 64 + lane];
  float f0 = blo(u), f1 = bhi(u);
  float ps = f0 * as_[2 * lane] + f1 * as_[2 * lane + 1];
  float pd = f0 * ad_[2 * lane] + f1 * ad_[2 * lane + 1];
#pragma unroll
  for (int o = 16; o > 0; o >>= 1) {  // half-wave reduce (feats of one head per half)
    ps += __shfl_xor(ps, o, 64);
    pd += __shfl_xor(pd, o, 64);
  }
  if (lane == 0)  { es[2 * n] = ps;     ed[2 * n] = pd; }
  if (lane == 32) { es[2 * n + 1] = ps; ed[2 * n + 1] = pd; }
}

// ---------- edge aggregation + combine (layers 1&2); one wave per dst ----------
__global__ __launch_bounds__(256) void k_agg(
    const int* __restrict__ rowptr, const int* __restrict__ col,
    const float* __restrict__ es, const float* __restrict__ ed,
    const unsigned* __restrict__ hb, const float* __restrict__ lin,
    const float* __restrict__ lb, const float* __restrict__ gb,
    float* __restrict__ xout, int N) {
  __shared__ float2 pbuf[4][128];
  int lane = threadIdx.x & 63;
  int w = threadIdx.x >> 6;
  int d = blockIdx.x * 4 + w;
  if (d >= N) return;
  int start = rowptr[d], end = rowptr[d + 1];
  float2 edv = *(const float2*)&ed[2 * d];
  int head_hi = lane >= 32;

  float s0 = 0.f, s1 = 0.f;
  for (int i = start + lane; i < end; i += 64) {
    int s = col[i];
    float2 ev = *(const float2*)&es[2 * s];
    float e0 = ev.x + edv.x; e0 = e0 > 0.f ? e0 : LEAKY * e0;
    float e1 = ev.y + edv.y; e1 = e1 > 0.f ? e1 : LEAKY * e1;
    float p0 = __expf(e0), p1 = __expf(e1);
    int j = i - start;
    if (j < 128) pbuf[w][j] = make_float2(p0, p1);
    s0 += p0; s1 += p1;
  }
  s0 = wsum(s0); s1 = wsum(s1);
  float inv = 1.0f / (head_hi ? s1 : s0);

  float acc0 = 0.f, acc1 = 0.f;
  int bounded = end < start + 128 ? end : start + 128;
  int i = start;
  for (; i + 4 <= bounded; i += 4) {
    int j = i - start;
    int c0 = col[i], c1 = col[i + 1], c2 = col[i + 2], c3 = col[i + 3];
    float2 w0 = pbuf[w][j], w1 = pbuf[w][j + 1], w2 = pbuf[w][j + 2], w3 = pbuf[w][j + 3];
    unsigned u0 = hb[(size_t)c0 * 64 + lane];
    unsigned u1 = hb[(size_t)c1 * 64 + lane];
    unsigned u2 = hb[(size_t)c2 * 64 + lane];
    unsigned u3 = hb[(size_t)c3 * 64 + lane];
    float f0 = head_hi ? w0.y : w0.x;
    float f1 = head_hi ? w1.y : w1.x;
    float f2 = head_hi ? w2.y : w2.x;
    float f3 = head_hi ? w3.y : w3.x;
    acc0 = fmaf(f0, blo(u0), acc0); acc1 = fmaf(f0, bhi(u0), acc1);
    acc0 = fmaf(f1, blo(u1), acc0); acc1 = fmaf(f1, bhi(u1), acc1);
    acc0 = fmaf(f2, blo(u2), acc0); acc1 = fmaf(f2, bhi(u2), acc1);
    acc0 = fmaf(f3, blo(u3), acc0); acc1 = fmaf(f3, bhi(u3), acc1);
  }
  for (; i < bounded; ++i) {
    int j = i - start;
    int c0 = col[i];
    float2 w0 = pbuf[w][j];
    unsigned u0 = hb[(size_t)c0 * 64 + lane];
    float f0 = head_hi ? w0.y : w0.x;
    acc0 = fmaf(f0, blo(u0), acc0); acc1 = fmaf(f0, bhi(u0), acc1);
  }
  for (; i < end; ++i) {
    int s = col[i];
    float2 ev = *(const float2*)&es[2 * s];
    float e0 = ev.x + edv.x; e0 = e0 > 0.f ? e0 : LEAKY * e0;
    float e1 = ev.y + edv.y; e1 = e1 > 0.f ? e1 : LEAKY * e1;
    float p0 = __expf(e0), p1 = __expf(e1);
    float f0 = head_hi ? p1 : p0;
    unsigned u0 = hb[(size_t)s * 64 + lane];
    acc0 = fmaf(f0, blo(u0), acc0); acc1 = fmaf(f0, bhi(u0), acc1);
  }

  int f = 2 * lane;
  size_t b = (size_t)d * 128 + f;
  float2 lv = *(const float2*)&lin[b];
  float2 lbv = *(const float2*)&lb[f];
  float2 gbv = *(const float2*)&gb[f];
  float v0 = lv.x + lbv.x + acc0 * inv + gbv.x;
  float v1 = lv.y + lbv.y + acc1 * inv + gbv.y;
  float2 o; o.x = v0 > 0.f ? v0 : 0.f; o.y = v1 > 0.f ? v1 : 0.f;
  *(float2*)&xout[b] = o;
}

// ---------- layer 3: BN-apply + tiny matmul + es/ed (1 head, 2 out feats) ----------
__global__ __launch_bounds__(256) void k_l3node(
    const float* __restrict__ x, const float* __restrict__ scale, const float* __restrict__ shift,
    const float* __restrict__ W3, const float* __restrict__ LW3,
    const float* __restrict__ as3, const float* __restrict__ ad3,
    float* h3, float* lin3, float* es3, float* ed3, int N) {
  int lane = threadIdx.x & 63;
  int n = blockIdx.x * 4 + (threadIdx.x >> 6);
  if (n >= N) return;
  float xn0 = x[(size_t)n * 128 + lane] * scale[lane] + shift[lane];
  float xn1 = x[(size_t)n * 128 + 64 + lane] * scale[64 + lane] + shift[64 + lane];
  float2 w0 = *(const float2*)&W3[lane * 2];
  float2 w1 = *(const float2*)&W3[(64 + lane) * 2];
  float2 l0 = *(const float2*)&LW3[lane * 2];
  float2 l1 = *(const float2*)&LW3[(64 + lane) * 2];
  float hc0 = wsum(xn0 * w0.x + xn1 * w1.x);
  float hc1 = wsum(xn0 * w0.y + xn1 * w1.y);
  float lc0 = wsum(xn0 * l0.x + xn1 * l1.x);
  float lc1 = wsum(xn0 * l0.y + xn1 * l1.y);
  if (lane == 0) {
    h3[2 * n] = hc0; h3[2 * n + 1] = hc1;
    lin3[2 * n] = lc0; lin3[2 * n + 1] = lc1;
    es3[n] = hc0 * as3[0] + hc1 * as3[1];
    ed3[n] = hc0 * ad3[0] + hc1 * ad3[1];
  }
}

// ---------- layer 3 edge aggregation + final output ----------
__global__ __launch_bounds__(256) void k_agg3(
    const int* __restrict__ rowptr, const int* __restrict__ col,
    const float* __restrict__ es, const float* __restrict__ ed,
    const float* __restrict__ h3, const float* __restrict__ lin3,
    const float* __restrict__ lb3, const float* __restrict__ gb3,
    float* __restrict__ out, int N) {
  int lane = threadIdx.x & 63;
  int d = blockIdx.x * 4 + (threadIdx.x >> 6);
  if (d >= N) return;
  int start = rowptr[d], end = rowptr[d + 1];
  float edd = ed[d];
  float ps = 0.f, a0 = 0.f, a1 = 0.f;
  for (int i = start + lane; i < end; i += 64) {
    int s = col[i];
    float e = es[s] + edd; e = e > 0.f ? e : LEAKY * e;
    float p = __expf(e);
    float2 hv = *(const float2*)&h3[2 * s];
    ps += p; a0 += p * hv.x; a1 += p * hv.y;
  }
  ps = wsum(ps); a0 = wsum(a0); a1 = wsum(a1);
  if (lane < 2) {
    float a = (lane == 0 ? a0 : a1) / ps;
    float v = lin3[2 * d + lane] + lb3[lane] + a + gb3[lane];
    out[2 * d + lane] = v > 0.f ? v : 0.f;
  }
}

extern "C" void kernel_launch(void* const* d_in, const int* in_sizes, int n_in,
                              void* d_out, int out_size, void* d_ws, size_t ws_size,
                              hipStream_t stream) {
  const float* x   = (const float*)d_in[0];
  const void*  ei  = d_in[1];
  const float* W1  = (const float*)d_in[2];
  const float* as1 = (const float*)d_in[3];
  const float* ad1 = (const float*)d_in[4];
  const float* gb1 = (const float*)d_in[5];
  const float* lw1 = (const float*)d_in[6];
  const float* lb1 = (const float*)d_in[7];
  const float* bg1 = (const float*)d_in[8];
  const float* bb1 = (const float*)d_in[9];
  const float* W2  = (const float*)d_in[10];
  const float* as2 = (const float*)d_in[11];
  const float* ad2 = (const float*)d_in[12];
  const float* gb2 = (const float*)d_in[13];
  const float* lw2 = (const float*)d_in[14];
  const float* lb2 = (const float*)d_in[15];
  const float* bg2 = (const float*)d_in[16];
  const float* bb2 = (const float*)d_in[17];
  const float* W3  = (const float*)d_in[18];
  const float* as3 = (const float*)d_in[19];
  const float* ad3 = (const float*)d_in[20];
  const float* gb3 = (const float*)d_in[21];
  const float* lw3 = (const float*)d_in[22];
  const float* lb3 = (const float*)d_in[23];
  const float* bg3 = (const float*)d_in[24];
  const float* bb3 = (const float*)d_in[25];
  float* out = (float*)d_out;

  int N = in_sizes[0] / 128;
  int E = in_sizes[1] / 2;
  int M = E + N;
  int nb = (N + 255) >> 8;
  int nblk = (M + BCHUNK - 1) / BCHUNK;

  char* wsp = (char*)d_ws;
  size_t off = 0;
  auto alloc = [&](size_t bytes) -> void* {
    void* p = wsp + off;
    off = (off + bytes + 255) & ~(size_t)255;
    return p;
  };
  int* flag     = (int*)alloc(4);
  int* rowptr   = (int*)alloc(((size_t)N + 1) * 4);
  int* col      = (int*)alloc((size_t)M * 4);
  unsigned* tmp = (unsigned*)alloc((size_t)M * 4);
  int* counts   = (int*)alloc(((size_t)nb * nblk + 1) * 4);
  float* sums  = (float*)alloc(3 * 256 * 4);
  float* scl   = (float*)alloc(3 * 256 * 4);
  unsigned short* Bp1 = (unsigned short*)alloc(4096 * 16);
  unsigned short* Bp2 = (unsigned short*)alloc(4096 * 16);
  unsigned* hbp = (unsigned*)alloc((size_t)N * 64 * 4);  // packed-bf16 h
  float* lin   = (float*)alloc((size_t)N * 128 * 4);
  float* x2    = (float*)alloc((size_t)N * 128 * 4);
  float* es    = (float*)alloc((size_t)N * 2 * 4);
  float* edb   = (float*)alloc((size_t)N * 2 * 4);
  float* h3    = (float*)alloc((size_t)N * 2 * 4);
  float* lin3  = (float*)alloc((size_t)N * 2 * 4);
  float* es3   = (float*)alloc((size_t)N * 4);
  float* ed3   = (float*)alloc((size_t)N * 4);
  (void)ws_size; (void)n_in; (void)out_size;

  hipMemsetAsync(sums, 0, 3 * 256 * 4, stream);

  // CSR build via bucketed counting sort (shared across all 3 layers)
  k_probe<<<1, 64, 0, stream>>>(ei, N, flag);
  k_binA<<<nblk, 256, 0, stream>>>(ei, flag, E, M, nb, nblk, counts);
  k_binScan<<<1, 1024, 0, stream>>>(counts, nb * nblk);
  k_binC<<<nblk, 256, 0, stream>>>(ei, flag, E, M, nb, nblk, counts, tmp);
  k_binD<<<nb, 256, 0, stream>>>(tmp, counts, nb, nblk, M, N, rowptr, col);

  // weight prep (bf16, fragment-ordered)
  k_prepB<<<16, 256, 0, stream>>>(W1, lw1, Bp1);
  k_prepB<<<16, 256, 0, stream>>>(W2, lw2, Bp2);

  int gnode = (N + 3) / 4;
  int gmm = (N + 31) / 32;

  // ---- layer 1 ----
  k_bnstats<<<1024, 128, 0, stream>>>(x, N, sums);
  k_bnfin<<<1, 128, 0, stream>>>(sums, bg1, bb1, N, scl, scl + 128);
  k_mm<<<gmm, 256, 0, stream>>>(x, scl, scl + 128, Bp1, hbp, lin, N);
  k_esed<<<gnode, 256, 0, stream>>>(hbp, as1, ad1, es, edb, N);
  k_agg<<<gnode, 256, 0, stream>>>(rowptr, col, es, edb, hbp, lin, lb1, gb1, x2, N);

  // ---- layer 2 ----
  k_bnstats<<<1024, 128, 0, stream>>>(x2, N, sums + 256);
  k_bnfin<<<1, 128, 0, stream>>>(sums + 256, bg2, bb2, N, scl + 256, scl + 384);
  k_mm<<<gmm, 256, 0, stream>>>(x2, scl + 256, scl + 384, Bp2, hbp, lin, N);
  k_esed<<<gnode, 256, 0, stream>>>(hbp, as2, ad2, es, edb, N);
  k_agg<<<gnode, 256, 0, stream>>>(rowptr, col, es, edb, hbp, lin, lb2, gb2, x2, N);

  // ---- layer 3 ----
  k_bnstats<<<1024, 128, 0, stream>>>(x2, N, sums + 512);
  k_bnfin<<<1, 128, 0, stream>>>(sums + 512, bg3, bb3, N, scl + 512, scl + 640);
  k_l3node<<<gnode, 256, 0, stream>>>(x2, scl + 512, scl + 640, W3, lw3, as3, ad3,
                                      h3, lin3, es3, ed3, N);
  k_agg3<<<gnode, 256, 0, stream>>>(rowptr, col, es3, ed3, h3, lin3, lb3, gb3, out, N);
}